// Round 17
// baseline (5388.298 us; speedup 1.0000x reference)
//
#include <hip/hip_runtime.h>
#include <cmath>

// Problem constants
#define NTAG    12
#define TAG_START 10
#define TAG_STOP  11
#define NEGV    (-10000.0f)

typedef unsigned int uint32;
typedef unsigned short u16;
typedef __attribute__((ext_vector_type(8))) short bf16x8;
typedef __attribute__((ext_vector_type(4))) float f32x4;

#define SDOT8(a, b, c) __builtin_amdgcn_sdot8((int)(a), (int)(b), (c), false)

// bf16 <-> f32 helpers
__device__ inline float b2f(u16 h) {
    union { uint32 u; float f; } v; v.u = ((uint32)h) << 16; return v.f;
}
__device__ inline u16 f2b(float f) {
    union { float f; uint32 u; } v; v.f = f;
    uint32 u = v.u;
    uint32 r = (u + 0x7FFFu + ((u >> 16) & 1u)) >> 16;
    return (u16)r;
}
__device__ inline uint32 f2b2(float a, float b) {
    return (uint32)f2b(a) | ((uint32)f2b(b) << 16);
}
__device__ inline float flo(uint32 u) {
    union { uint32 u; float f; } v; v.u = u << 16; return v.f;
}
__device__ inline float fhi(uint32 u) {
    union { uint32 u; float f; } v; v.u = u & 0xFFFF0000u; return v.f;
}

// ---------------------------------------------------------------------------
// ws layout (bytes):
//   Wn2     u32 [2 dir][64 oct][512 u][4 ty]  1,048,576  int4 W_hh (dot8 nibbles)
//   sS      f32 [2 dir][512 u][4 ty]             16,384  per-row scale
//   Wihb    u16 [4096][512]                   4,194,304  bf16 W_ih (f then b)
//   biascat f32 [4096]                           16,384  bias (f then b)
//   Ft      f32 [32768][12]                   1,572,864  feats
//   Lout    bf16 [32768][1024]               67,108,864  bilstm output
//   Gx      bf16 [NB*512][4096]           NB*4,194,304   gate preacts (chunk)
// ---------------------------------------------------------------------------

// --- Kernel 0: pack W_ih + bias to bf16 concat -------------------------------
__global__ __launch_bounds__(256) void k_packw(const float* __restrict__ Wf,
        const float* __restrict__ Wb, const float* __restrict__ bf,
        const float* __restrict__ bb, u16* __restrict__ Wihb,
        float* __restrict__ biascat) {
    int g = blockIdx.x;           // 0..4095
    const float* src = (g < 2048) ? (Wf + (size_t)g * 512)
                                  : (Wb + (size_t)(g - 2048) * 512);
    for (int k = threadIdx.x; k < 512; k += 256)
        Wihb[(size_t)g * 512 + k] = f2b(src[k]);
    if (threadIdx.x == 0)
        biascat[g] = (g < 2048) ? bf[g] : bb[g - 2048];
}

// --- Kernel 1: pack W_hh as dot8 nibbles, [dir][oct][unit][ty] layout. ------
__global__ __launch_bounds__(64) void k_pack(const float* __restrict__ Wf,
                                             const float* __restrict__ Wb,
                                             uint32* __restrict__ Wn2,
                                             float* __restrict__ sS) {
    int e = blockIdx.x;                 // 0..4095
    int dir = e >> 11, g = e & 2047;
    int ty = g >> 9, u = g & 511;
    const float* W = (dir ? Wb : Wf) + (size_t)g * 512;
    int t = threadIdx.x;                // oct index
    float w[8];
    float m = 0.f;
    #pragma unroll
    for (int i = 0; i < 8; ++i) {
        w[i] = W[t * 8 + i];
        m = fmaxf(m, fabsf(w[i]));
    }
    #pragma unroll
    for (int off = 32; off > 0; off >>= 1)
        m = fmaxf(m, __shfl_xor(m, off));
    float s = (m > 0.f) ? (m / 7.f) : 1.f;
    float inv = 1.f / s;
    uint32 d = 0;
    #pragma unroll
    for (int k = 0; k < 8; ++k) {
        uint32 qv = (uint32)((int)rintf(w[k] * inv)) & 0xFu;
        d |= qv << (4 * k);
    }
    Wn2[(((size_t)dir * 64 + t) * 512 + u) * 4 + ty] = d;
    if (t == 0) sS[((size_t)dir * 512 + u) * 4 + ty] = s / 7.f;
}

// --- Kernel 2: fused gather + input GEMM, bf16 MFMA (unchanged) -------------
__global__ __launch_bounds__(256) void k_gemm(const int* __restrict__ sent,
        const float* __restrict__ emb, const u16* __restrict__ Wihb,
        const float* __restrict__ biascat, u16* __restrict__ Gxc, int b0c) {
    __shared__ __align__(16) u16 As[128][72];
    __shared__ __align__(16) u16 Bs[128][72];
    __shared__ int ssent[128];

    int bid = blockIdx.x;
    int nb = bid & 31, mb = bid >> 5;
    int M0 = mb << 7, N0 = nb << 7;
    int t = threadIdx.x;
    int w = t >> 6, l = t & 63;
    int wr = w >> 1, wc = w & 1;

    if (t < 128) ssent[t] = sent[b0c * 512 + M0 + t];

    f32x4 zero = {0.f, 0.f, 0.f, 0.f};
    f32x4 acc[4][4];
    #pragma unroll
    for (int i = 0; i < 4; ++i)
        #pragma unroll
        for (int j = 0; j < 4; ++j) acc[i][j] = zero;

    int srow = t >> 3;
    int skc  = (t & 7) << 3;
    __syncthreads();

    for (int k0 = 0; k0 < 512; k0 += 64) {
        #pragma unroll
        for (int i = 0; i < 4; ++i) {
            int r = srow + (i << 5);
            const float* srcA = emb + (size_t)ssent[r] * 512 + k0 + skc;
            float4 f0 = *(const float4*)srcA;
            float4 f1 = *(const float4*)(srcA + 4);
            uint4 pa;
            pa.x = f2b2(f0.x, f0.y); pa.y = f2b2(f0.z, f0.w);
            pa.z = f2b2(f1.x, f1.y); pa.w = f2b2(f1.z, f1.w);
            *(uint4*)&As[r][skc] = pa;
            uint4 pb = *(const uint4*)(Wihb + (size_t)(N0 + r) * 512 + k0 + skc);
            *(uint4*)&Bs[r][skc] = pb;
        }
        __syncthreads();
        int lrow = l & 15, lk = (l >> 4) << 3;
        #pragma unroll
        for (int kk = 0; kk < 64; kk += 32) {
            bf16x8 af[4], bfr[4];
            #pragma unroll
            for (int i = 0; i < 4; ++i)
                af[i] = *(const bf16x8*)&As[(wr << 6) + (i << 4) + lrow][kk + lk];
            #pragma unroll
            for (int j = 0; j < 4; ++j)
                bfr[j] = *(const bf16x8*)&Bs[(wc << 6) + (j << 4) + lrow][kk + lk];
            #pragma unroll
            for (int i = 0; i < 4; ++i)
                #pragma unroll
                for (int j = 0; j < 4; ++j)
                    acc[i][j] = __builtin_amdgcn_mfma_f32_16x16x32_bf16(
                        af[i], bfr[j], acc[i][j], 0, 0, 0);
        }
        __syncthreads();
    }

    int lrow = l & 15, lq = l >> 4;
    #pragma unroll
    for (int j = 0; j < 4; ++j) {
        int col = N0 + (wc << 6) + (j << 4) + lrow;
        float bv = biascat[col];
        #pragma unroll
        for (int i = 0; i < 4; ++i) {
            int rbase = M0 + (wr << 6) + (i << 4) + (lq << 2);
            #pragma unroll
            for (int r = 0; r < 4; ++r)
                Gxc[(size_t)(rbase + r) * 4096 + col] = f2b(acc[i][j][r] + bv);
        }
    }
}

// 16 dot8 for a 4-oct group: h = 4 h-dwords, w0..w3 = per-oct gate dwords
#define D8_GRP(h, w0, w1, w2, w3)                                          \
    do {                                                                   \
        a0 = SDOT8((h).x, (w0).x, a0); a1 = SDOT8((h).x, (w0).y, a1);      \
        a2 = SDOT8((h).x, (w0).z, a2); a3 = SDOT8((h).x, (w0).w, a3);      \
        a0 = SDOT8((h).y, (w1).x, a0); a1 = SDOT8((h).y, (w1).y, a1);      \
        a2 = SDOT8((h).y, (w1).z, a2); a3 = SDOT8((h).y, (w1).w, a3);      \
        a0 = SDOT8((h).z, (w2).x, a0); a1 = SDOT8((h).z, (w2).y, a1);      \
        a2 = SDOT8((h).z, (w2).z, a2); a3 = SDOT8((h).z, (w2).w, a3);      \
        a0 = SDOT8((h).w, (w3).x, a0); a1 = SDOT8((h).w, (w3).y, a1);      \
        a2 = SDOT8((h).w, (w3).z, a2); a3 = SDOT8((h).w, (w3).w, a3);      \
    } while (0)

// --- Kernel 3: BiLSTM recurrence, cross-barrier pipelined weight stream -----
// amdgpu_waves_per_eu(4,4): LDS already caps at 1 block/CU (16 waves = 4/EU),
// so cap the allocator's occupancy target too -> full 128-VGPR budget.
// sw[16] staged loads are issued for step si+1 BEFORE the barriers of step si
// (weights don't depend on h; private-register loads legally cross s_barrier),
// so the stream flies during the activation window. Integer sums unchanged ->
// gates bit-identical to rounds 11-16 (absmax must stay exactly 6.0).
__global__ __attribute__((amdgpu_waves_per_eu(4, 4)))
__launch_bounds__(1024) void k_lstm(const u16* __restrict__ Gxc,
        const uint32* __restrict__ Wn2, const float* __restrict__ sS,
        u16* __restrict__ Lout, int b0c) {
    int bid = blockIdx.x;
    int dir, slot;
    if (gridDim.x >= 8) {
        int xid = bid & 7, q = bid >> 3;
        dir  = xid >> 2;                 // XCDs 0-3 dir0, 4-7 dir1
        slot = (xid & 3) | (q << 2);
    } else {
        dir  = bid & 1;
        slot = bid >> 1;
    }
    int b  = b0c + slot;
    int lb = slot;

    __shared__ __align__(16) uint32 wlds[16][2048];  // 128 KB: octs 0..15
    __shared__ __align__(16) uint32 hq4[2][64];      // i4 h, parity dbuf
    __shared__ __align__(16) int4   pbuf[512];       // 8 KB upper-half partials

    int t = threadIdx.x;
    int u = t & 511;                    // owned unit
    int half = t >> 9;                  // 0 lower, 1 upper (wave-aligned)
    if (t < 128) hq4[t >> 6][t & 63] = 0u;
    float cs = 0.f;

    const uint32* wsrc = Wn2 + (size_t)dir * (64 * 2048);
    {   // preload LDS tier: 8192 uint4, 1024 threads x 8
        const uint4* src = (const uint4*)wsrc;
        uint4* dst = (uint4*)wlds;
        #pragma unroll
        for (int i = 0; i < 8; ++i)
            dst[t + i * 1024] = src[t + i * 1024];
    }
    float4 sc = {0.f, 0.f, 0.f, 0.f};
    const u16* gx = Gxc;
    if (half == 0) {
        sc = *(const float4*)(sS + ((size_t)dir * 512 + u) * 4);
        gx = Gxc + (size_t)lb * 512 * 4096 + (dir << 11) + u;
    }
    int ldsg0 = half ? 2 : 0;                                 // LDS h-groups
    const uint32* sp = wsrc + (size_t)(half ? 40 : 16) * 2048 + (u << 2);
    int hgs0 = half ? 10 : 4;                                 // streamed h-groups
    int sh = (u & 7) << 2;

    // prologue: stage first step's bulk streamed groups (16 b128 loads)
    uint4 sw[16];
    #pragma unroll
    for (int i = 0; i < 16; ++i)
        sw[i] = *(const uint4*)(sp + (size_t)i * 2048);
    __syncthreads();

    for (int si = 0; si < 512; ++si) {
        int s = dir ? (511 - si) : si;
        int par = si & 1;
        const uint4* hg = (const uint4*)hq4[par];

        // Gx preact loads (longest latency; consumed in activation phase)
        u16 g0v = 0, g1v = 0, g2v = 0, g3v = 0;
        if (half == 0) {
            const u16* gs = gx + (size_t)s * 4096;
            g0v = gs[0]; g1v = gs[512]; g2v = gs[1024]; g3v = gs[1536];
        }

        int a0 = 0, a1 = 0, a2 = 0, a3 = 0;

        // LDS tier: 2 groups
        #pragma unroll
        for (int p = 0; p < 2; ++p) {
            int gp = ldsg0 + p;
            uint4 h  = hg[gp];
            uint4 w0 = *(const uint4*)&wlds[4 * gp + 0][u << 2];
            uint4 w1 = *(const uint4*)&wlds[4 * gp + 1][u << 2];
            uint4 w2 = *(const uint4*)&wlds[4 * gp + 2][u << 2];
            uint4 w3 = *(const uint4*)&wlds[4 * gp + 3][u << 2];
            D8_GRP(h, w0, w1, w2, w3);
        }
        // staged streamed groups 0..3 (loads issued last step, long since landed)
        #pragma unroll
        for (int p = 0; p < 4; ++p) {
            uint4 h = hg[hgs0 + p];
            D8_GRP(h, sw[4 * p], sw[4 * p + 1], sw[4 * p + 2], sw[4 * p + 3]);
        }
        // tail streamed groups 4..5, load+consume inline
        #pragma unroll
        for (int p = 4; p < 6; ++p) {
            uint4 h  = hg[hgs0 + p];
            uint4 w0 = *(const uint4*)(sp + (size_t)(4 * p + 0) * 2048);
            uint4 w1 = *(const uint4*)(sp + (size_t)(4 * p + 1) * 2048);
            uint4 w2 = *(const uint4*)(sp + (size_t)(4 * p + 2) * 2048);
            uint4 w3 = *(const uint4*)(sp + (size_t)(4 * p + 3) * 2048);
            D8_GRP(h, w0, w1, w2, w3);
        }

        // re-issue staged loads for step si+1 BEFORE the barriers:
        // they fly through B1 + activation + B2 (same addresses every step)
        #pragma unroll
        for (int i = 0; i < 16; ++i)
            sw[i] = *(const uint4*)(sp + (size_t)i * 2048);

        if (half) pbuf[u] = make_int4(a0, a1, a2, a3);
        __syncthreads();

        if (half == 0) {
            int4 pu = pbuf[u];
            a0 += pu.x; a1 += pu.y; a2 += pu.z; a3 += pu.w;
            float pi = b2f(g0v) + sc.x * (float)a0;
            float pf = b2f(g1v) + sc.y * (float)a1;
            float pg = b2f(g2v) + sc.z * (float)a2;
            float po = b2f(g3v) + sc.w * (float)a3;
            float iv  = 1.f / (1.f + expf(-pi));
            float fvv = 1.f / (1.f + expf(-pf));
            float gv  = tanhf(pg);
            float ov  = 1.f / (1.f + expf(-po));
            float cn = fvv * cs + iv * gv;
            float hn = ov * tanhf(cn);
            cs = cn;
            uint32 v = (((uint32)(int)rintf(hn * 7.f)) & 0xFu) << sh;
            v |= __shfl_xor(v, 1); v |= __shfl_xor(v, 2); v |= __shfl_xor(v, 4);
            if ((u & 7) == 0) hq4[par ^ 1][u >> 3] = v;
            Lout[((size_t)b * 512 + s) * 1024 + (dir << 9) + u] = f2b(hn);
        }
        __syncthreads();
    }
}

// --- Kernel 4: feats = Lout(bf16) @ W_out^T + b_out ------------------------
__global__ __launch_bounds__(256) void k_feats(const u16* __restrict__ Lout,
        const float* __restrict__ Wout, const float* __restrict__ bout,
        float* __restrict__ Ft) {
    __shared__ __align__(16) float Wl[12 * 1024];
    for (int i = threadIdx.x; i < 12 * 1024; i += 256) Wl[i] = Wout[i];
    __syncthreads();
    int wv = threadIdx.x >> 6, lane = threadIdx.x & 63;
    size_t row = (size_t)blockIdx.x * 4 + wv;
    const uint4* xr = (const uint4*)(Lout + row * 1024);
    float acc[12];
    #pragma unroll
    for (int tg = 0; tg < 12; ++tg) acc[tg] = 0.f;
    #pragma unroll
    for (int c = 0; c < 2; ++c) {
        int e8 = lane + (c << 6);
        uint4 xv = xr[e8];
        float x0 = flo(xv.x), x1 = fhi(xv.x);
        float x2 = flo(xv.y), x3 = fhi(xv.y);
        float x4 = flo(xv.z), x5 = fhi(xv.z);
        float x6 = flo(xv.w), x7 = fhi(xv.w);
        #pragma unroll
        for (int tg = 0; tg < 12; ++tg) {
            const float* wpt = &Wl[tg * 1024 + (e8 << 3)];
            float4 wa = *(const float4*)wpt;
            float4 wb = *(const float4*)(wpt + 4);
            acc[tg] += x0 * wa.x + x1 * wa.y + x2 * wa.z + x3 * wa.w
                     + x4 * wb.x + x5 * wb.y + x6 * wb.z + x7 * wb.w;
        }
    }
    #pragma unroll
    for (int tg = 0; tg < 12; ++tg) {
        #pragma unroll
        for (int off = 32; off > 0; off >>= 1)
            acc[tg] += __shfl_xor(acc[tg], off);
    }
    float v = 0.f;
    #pragma unroll
    for (int tg = 0; tg < 12; ++tg)
        if (lane == tg) v = acc[tg];
    if (lane < 12) Ft[row * 12 + lane] = v + bout[lane];
}

// --- Kernel 5: Viterbi per batch (1 wave). ---------------------------------
__global__ __launch_bounds__(64) void k_viterbi(const float* __restrict__ Ft,
        const float* __restrict__ trans, float* __restrict__ out) {
    int b = blockIdx.x;
    int lane = threadIdx.x;
    __shared__ unsigned char bps[512][12];
    float tr[12];
    #pragma unroll
    for (int p = 0; p < 12; ++p)
        tr[p] = (lane < 12) ? trans[lane * 12 + p] : 0.f;
    float fv = (lane == TAG_START) ? 0.f : NEGV;
    const float* fb = Ft + (size_t)b * 512 * 12;
    for (int s = 0; s < 512; ++s) {
        float m = -3.4e38f;
        int bp = 0;
        #pragma unroll
        for (int p = 0; p < 12; ++p) {
            float v = __shfl(fv, p) + tr[p];
            if (v > m) { m = v; bp = p; }
        }
        float feat = (lane < 12) ? fb[s * 12 + lane] : 0.f;
        fv = m + feat;
        if (lane < 12) bps[s][lane] = (unsigned char)bp;
    }
    float term = fv + ((lane < 12) ? trans[TAG_STOP * 12 + lane] : 0.f);
    __syncthreads();
    float best = -3.4e38f; int tag = 0;
    #pragma unroll
    for (int p = 0; p < 12; ++p) {
        float v = __shfl(term, p);
        if (v > best) { best = v; tag = p; }
    }
    if (lane == 0) {
        out[b] = best;
        int tg = tag;
        for (int s = 511; s >= 0; --s) {
            out[64 + (size_t)b * 512 + s] = (float)tg;
            tg = bps[s][tg];
        }
    }
}

extern "C" void kernel_launch(void* const* d_in, const int* in_sizes, int n_in,
                              void* d_out, int out_size, void* d_ws, size_t ws_size,
                              hipStream_t stream) {
    const int*   sent   = (const int*)  d_in[0];
    const float* emb    = (const float*)d_in[1];
    const float* W_ih_f = (const float*)d_in[2];
    const float* W_hh_f = (const float*)d_in[3];
    const float* b_f    = (const float*)d_in[4];
    const float* W_ih_b = (const float*)d_in[5];
    const float* W_hh_b = (const float*)d_in[6];
    const float* b_b    = (const float*)d_in[7];
    const float* W_out  = (const float*)d_in[8];
    const float* b_out  = (const float*)d_in[9];
    const float* trans  = (const float*)d_in[10];
    float* out = (float*)d_out;

    char* wsB = (char*)d_ws;
    size_t off = 0;
    uint32* Wn2    = (uint32*)(wsB + off); off += 1048576;
    float*  sS     = (float*) (wsB + off); off += 16384;
    u16*    Wihb   = (u16*)   (wsB + off); off += 4194304;
    float*  biascat= (float*) (wsB + off); off += 16384;
    float*  Ft     = (float*) (wsB + off); off += 1572864;
    u16*    Lout   = (u16*)   (wsB + off); off += 67108864;
    size_t fixed = off;
    u16*    Gxc    = (u16*)   (wsB + off);

    int NB = 64;
    while (NB > 2 && fixed + (size_t)NB * 4194304ull > ws_size) NB >>= 1;

    k_packw<<<4096, 256, 0, stream>>>(W_ih_f, W_ih_b, b_f, b_b, Wihb, biascat);
    k_pack <<<4096, 64, 0, stream>>>(W_hh_f, W_hh_b, Wn2, sS);
    for (int c = 0; c < 64; c += NB) {
        k_gemm<<<NB * 128, 256, 0, stream>>>(sent, emb, Wihb, biascat, Gxc, c);
        k_lstm<<<NB * 2, 1024, 0, stream>>>(Gxc, Wn2, sS, Lout, c);
    }
    k_feats  <<<8192, 256, 0, stream>>>(Lout, W_out, b_out, Ft);
    k_viterbi<<<64, 64, 0, stream>>>(Ft, trans, out);
}

// Round 18
// 1686.463 us; speedup vs baseline: 3.1950x; 3.1950x over previous
//
#include <hip/hip_runtime.h>
#include <cmath>

// Problem constants
#define NTAG    12
#define TAG_START 10
#define TAG_STOP  11
#define NEGV    (-10000.0f)

typedef unsigned int uint32;
typedef unsigned short u16;
typedef __attribute__((ext_vector_type(8))) short bf16x8;
typedef __attribute__((ext_vector_type(4))) float f32x4;

#define SDOT8(a, b, c) __builtin_amdgcn_sdot8((int)(a), (int)(b), (c), false)

// bf16 <-> f32 helpers
__device__ inline float b2f(u16 h) {
    union { uint32 u; float f; } v; v.u = ((uint32)h) << 16; return v.f;
}
__device__ inline u16 f2b(float f) {
    union { float f; uint32 u; } v; v.f = f;
    uint32 u = v.u;
    uint32 r = (u + 0x7FFFu + ((u >> 16) & 1u)) >> 16;
    return (u16)r;
}
__device__ inline uint32 f2b2(float a, float b) {
    return (uint32)f2b(a) | ((uint32)f2b(b) << 16);
}
__device__ inline float flo(uint32 u) {
    union { uint32 u; float f; } v; v.u = u << 16; return v.f;
}
__device__ inline float fhi(uint32 u) {
    union { uint32 u; float f; } v; v.u = u & 0xFFFF0000u; return v.f;
}

// ---------------------------------------------------------------------------
// ws layout (bytes):
//   Wn2     u32 [2 dir][64 oct][512 u][4 ty]  1,048,576  int4 W_hh (dot8 nibbles)
//   sS      f32 [2 dir][512 u][4 ty]             16,384  per-row scale
//   Wihb    u16 [4096][512]                   4,194,304  bf16 W_ih (f then b)
//   biascat f32 [4096]                           16,384  bias (f then b)
//   Ft      f32 [32768][12]                   1,572,864  feats
//   Lout    bf16 [32768][1024]               67,108,864  bilstm output
//   Gx      bf16 [NB*512][4096]           NB*4,194,304   gate preacts (chunk)
// ---------------------------------------------------------------------------

// --- Kernel 0: pack W_ih + bias to bf16 concat -------------------------------
__global__ __launch_bounds__(256) void k_packw(const float* __restrict__ Wf,
        const float* __restrict__ Wb, const float* __restrict__ bf,
        const float* __restrict__ bb, u16* __restrict__ Wihb,
        float* __restrict__ biascat) {
    int g = blockIdx.x;           // 0..4095
    const float* src = (g < 2048) ? (Wf + (size_t)g * 512)
                                  : (Wb + (size_t)(g - 2048) * 512);
    for (int k = threadIdx.x; k < 512; k += 256)
        Wihb[(size_t)g * 512 + k] = f2b(src[k]);
    if (threadIdx.x == 0)
        biascat[g] = (g < 2048) ? bf[g] : bb[g - 2048];
}

// --- Kernel 1: pack W_hh as dot8 nibbles, [dir][oct][unit][ty] layout. ------
__global__ __launch_bounds__(64) void k_pack(const float* __restrict__ Wf,
                                             const float* __restrict__ Wb,
                                             uint32* __restrict__ Wn2,
                                             float* __restrict__ sS) {
    int e = blockIdx.x;                 // 0..4095
    int dir = e >> 11, g = e & 2047;
    int ty = g >> 9, u = g & 511;
    const float* W = (dir ? Wb : Wf) + (size_t)g * 512;
    int t = threadIdx.x;                // oct index
    float w[8];
    float m = 0.f;
    #pragma unroll
    for (int i = 0; i < 8; ++i) {
        w[i] = W[t * 8 + i];
        m = fmaxf(m, fabsf(w[i]));
    }
    #pragma unroll
    for (int off = 32; off > 0; off >>= 1)
        m = fmaxf(m, __shfl_xor(m, off));
    float s = (m > 0.f) ? (m / 7.f) : 1.f;
    float inv = 1.f / s;
    uint32 d = 0;
    #pragma unroll
    for (int k = 0; k < 8; ++k) {
        uint32 qv = (uint32)((int)rintf(w[k] * inv)) & 0xFu;
        d |= qv << (4 * k);
    }
    Wn2[(((size_t)dir * 64 + t) * 512 + u) * 4 + ty] = d;
    if (t == 0) sS[((size_t)dir * 512 + u) * 4 + ty] = s / 7.f;
}

// --- Kernel 2: fused gather + input GEMM, bf16 MFMA (unchanged) -------------
__global__ __launch_bounds__(256) void k_gemm(const int* __restrict__ sent,
        const float* __restrict__ emb, const u16* __restrict__ Wihb,
        const float* __restrict__ biascat, u16* __restrict__ Gxc, int b0c) {
    __shared__ __align__(16) u16 As[128][72];
    __shared__ __align__(16) u16 Bs[128][72];
    __shared__ int ssent[128];

    int bid = blockIdx.x;
    int nb = bid & 31, mb = bid >> 5;
    int M0 = mb << 7, N0 = nb << 7;
    int t = threadIdx.x;
    int w = t >> 6, l = t & 63;
    int wr = w >> 1, wc = w & 1;

    if (t < 128) ssent[t] = sent[b0c * 512 + M0 + t];

    f32x4 zero = {0.f, 0.f, 0.f, 0.f};
    f32x4 acc[4][4];
    #pragma unroll
    for (int i = 0; i < 4; ++i)
        #pragma unroll
        for (int j = 0; j < 4; ++j) acc[i][j] = zero;

    int srow = t >> 3;
    int skc  = (t & 7) << 3;
    __syncthreads();

    for (int k0 = 0; k0 < 512; k0 += 64) {
        #pragma unroll
        for (int i = 0; i < 4; ++i) {
            int r = srow + (i << 5);
            const float* srcA = emb + (size_t)ssent[r] * 512 + k0 + skc;
            float4 f0 = *(const float4*)srcA;
            float4 f1 = *(const float4*)(srcA + 4);
            uint4 pa;
            pa.x = f2b2(f0.x, f0.y); pa.y = f2b2(f0.z, f0.w);
            pa.z = f2b2(f1.x, f1.y); pa.w = f2b2(f1.z, f1.w);
            *(uint4*)&As[r][skc] = pa;
            uint4 pb = *(const uint4*)(Wihb + (size_t)(N0 + r) * 512 + k0 + skc);
            *(uint4*)&Bs[r][skc] = pb;
        }
        __syncthreads();
        int lrow = l & 15, lk = (l >> 4) << 3;
        #pragma unroll
        for (int kk = 0; kk < 64; kk += 32) {
            bf16x8 af[4], bfr[4];
            #pragma unroll
            for (int i = 0; i < 4; ++i)
                af[i] = *(const bf16x8*)&As[(wr << 6) + (i << 4) + lrow][kk + lk];
            #pragma unroll
            for (int j = 0; j < 4; ++j)
                bfr[j] = *(const bf16x8*)&Bs[(wc << 6) + (j << 4) + lrow][kk + lk];
            #pragma unroll
            for (int i = 0; i < 4; ++i)
                #pragma unroll
                for (int j = 0; j < 4; ++j)
                    acc[i][j] = __builtin_amdgcn_mfma_f32_16x16x32_bf16(
                        af[i], bfr[j], acc[i][j], 0, 0, 0);
        }
        __syncthreads();
    }

    int lrow = l & 15, lq = l >> 4;
    #pragma unroll
    for (int j = 0; j < 4; ++j) {
        int col = N0 + (wc << 6) + (j << 4) + lrow;
        float bv = biascat[col];
        #pragma unroll
        for (int i = 0; i < 4; ++i) {
            int rbase = M0 + (wr << 6) + (i << 4) + (lq << 2);
            #pragma unroll
            for (int r = 0; r < 4; ++r)
                Gxc[(size_t)(rbase + r) * 4096 + col] = f2b(acc[i][j][r] + bv);
        }
    }
}

// 16 dot8 for a 4-oct group: h = 4 h-dwords, w0..w3 = per-oct gate dwords
#define D8_GRP(h, w0, w1, w2, w3)                                          \
    do {                                                                   \
        a0 = SDOT8((h).x, (w0).x, a0); a1 = SDOT8((h).x, (w0).y, a1);      \
        a2 = SDOT8((h).x, (w0).z, a2); a3 = SDOT8((h).x, (w0).w, a3);      \
        a0 = SDOT8((h).y, (w1).x, a0); a1 = SDOT8((h).y, (w1).y, a1);      \
        a2 = SDOT8((h).y, (w1).z, a2); a3 = SDOT8((h).y, (w1).w, a3);      \
        a0 = SDOT8((h).z, (w2).x, a0); a1 = SDOT8((h).z, (w2).y, a1);      \
        a2 = SDOT8((h).z, (w2).z, a2); a3 = SDOT8((h).z, (w2).w, a3);      \
        a0 = SDOT8((h).w, (w3).x, a0); a1 = SDOT8((h).w, (w3).y, a1);      \
        a2 = SDOT8((h).w, (w3).z, a2); a3 = SDOT8((h).w, (w3).w, a3);      \
    } while (0)

// --- Kernel 3: BiLSTM recurrence (round-14 version, verbatim revert) --------
// 1024 threads, K-split halves + (inert) 8-oct register-tier request.
// Measured 1170 us; r15-r17 variants were all null or regressions.
__global__ __launch_bounds__(1024, 4) void k_lstm(const u16* __restrict__ Gxc,
        const uint32* __restrict__ Wn2, const float* __restrict__ sS,
        u16* __restrict__ Lout, int b0c) {
    int bid = blockIdx.x;
    int dir, slot;
    if (gridDim.x >= 8) {
        int xid = bid & 7, q = bid >> 3;
        dir  = xid >> 2;                 // XCDs 0-3 dir0, 4-7 dir1
        slot = (xid & 3) | (q << 2);
    } else {
        dir  = bid & 1;
        slot = bid >> 1;
    }
    int b  = b0c + slot;
    int lb = slot;

    __shared__ __align__(16) uint32 wlds[16][2048];  // 128 KB: octs 0..15
    __shared__ __align__(16) uint32 hq4[2][64];      // i4 h, parity dbuf
    __shared__ __align__(16) int4   pbuf[512];       // 8 KB upper-half partials

    int t = threadIdx.x;
    int u = t & 511;                    // owned unit
    int half = t >> 9;                  // 0 lower, 1 upper (wave-aligned)
    if (t < 128) hq4[t >> 6][t & 63] = 0u;
    float cs = 0.f;

    const uint32* wsrc = Wn2 + (size_t)dir * (64 * 2048);
    {   // preload LDS tier: 8192 uint4, 1024 threads x 8
        const uint4* src = (const uint4*)wsrc;
        uint4* dst = (uint4*)wlds;
        #pragma unroll
        for (int i = 0; i < 8; ++i)
            dst[t + i * 1024] = src[t + i * 1024];
    }
    // register tier request (compiler may sink; harmless)
    const uint32* rp = wsrc + (size_t)(half ? 40 : 16) * 2048 + (u << 2);
    uint4 wreg[8];
    #pragma unroll
    for (int i = 0; i < 8; ++i)
        wreg[i] = *(const uint4*)(rp + (size_t)i * 2048);

    float4 sc = {0.f, 0.f, 0.f, 0.f};
    const u16* gx = Gxc;
    if (half == 0) {
        sc = *(const float4*)(sS + ((size_t)dir * 512 + u) * 4);
        gx = Gxc + (size_t)lb * 512 * 4096 + (dir << 11) + u;
    }
    int ldsg0 = half ? 2 : 0;                                 // LDS h-groups
    int regg0 = half ? 10 : 4;                                // reg h-groups
    const uint32* sp = wsrc + (size_t)(half ? 48 : 24) * 2048 + (u << 2);
    int hgs0 = half ? 12 : 6;                                 // streamed h-groups
    int sh = (u & 7) << 2;
    __syncthreads();

    for (int si = 0; si < 512; ++si) {
        int s = dir ? (511 - si) : si;
        int par = si & 1;
        const uint4* hg = (const uint4*)hq4[par];

        // early Gx preact prefetch (lower half; L3 latency hides under dots)
        u16 g0v = 0, g1v = 0, g2v = 0, g3v = 0;
        if (half == 0) {
            const u16* gs = gx + (size_t)s * 4096;
            g0v = gs[0]; g1v = gs[512]; g2v = gs[1024]; g3v = gs[1536];
        }

        int a0 = 0, a1 = 0, a2 = 0, a3 = 0;

        // streamed tier: 4 groups (16 octs)
        #pragma unroll
        for (int p = 0; p < 4; ++p) {
            uint4 h  = hg[hgs0 + p];
            uint4 w0 = *(const uint4*)(sp + (size_t)(4 * p + 0) * 2048);
            uint4 w1 = *(const uint4*)(sp + (size_t)(4 * p + 1) * 2048);
            uint4 w2 = *(const uint4*)(sp + (size_t)(4 * p + 2) * 2048);
            uint4 w3 = *(const uint4*)(sp + (size_t)(4 * p + 3) * 2048);
            D8_GRP(h, w0, w1, w2, w3);
        }
        // register tier: 2 groups (8 octs)
        {
            uint4 h = hg[regg0];
            D8_GRP(h, wreg[0], wreg[1], wreg[2], wreg[3]);
            h = hg[regg0 + 1];
            D8_GRP(h, wreg[4], wreg[5], wreg[6], wreg[7]);
        }
        // LDS tier: 2 groups (8 octs)
        #pragma unroll
        for (int p = 0; p < 2; ++p) {
            int gp = ldsg0 + p;
            uint4 h  = hg[gp];
            uint4 w0 = *(const uint4*)&wlds[4 * gp + 0][u << 2];
            uint4 w1 = *(const uint4*)&wlds[4 * gp + 1][u << 2];
            uint4 w2 = *(const uint4*)&wlds[4 * gp + 2][u << 2];
            uint4 w3 = *(const uint4*)&wlds[4 * gp + 3][u << 2];
            D8_GRP(h, w0, w1, w2, w3);
        }

        if (half) pbuf[u] = make_int4(a0, a1, a2, a3);
        __syncthreads();

        if (half == 0) {
            int4 pu = pbuf[u];
            a0 += pu.x; a1 += pu.y; a2 += pu.z; a3 += pu.w;
            float pi = b2f(g0v) + sc.x * (float)a0;
            float pf = b2f(g1v) + sc.y * (float)a1;
            float pg = b2f(g2v) + sc.z * (float)a2;
            float po = b2f(g3v) + sc.w * (float)a3;
            float iv  = 1.f / (1.f + expf(-pi));
            float fvv = 1.f / (1.f + expf(-pf));
            float gv  = tanhf(pg);
            float ov  = 1.f / (1.f + expf(-po));
            float cn = fvv * cs + iv * gv;
            float hn = ov * tanhf(cn);
            cs = cn;
            uint32 v = (((uint32)(int)rintf(hn * 7.f)) & 0xFu) << sh;
            v |= __shfl_xor(v, 1); v |= __shfl_xor(v, 2); v |= __shfl_xor(v, 4);
            if ((u & 7) == 0) hq4[par ^ 1][u >> 3] = v;
            Lout[((size_t)b * 512 + s) * 1024 + (dir << 9) + u] = f2b(hn);
        }
        __syncthreads();
    }
}

// --- Kernel 4: feats = Lout(bf16) @ W_out^T + b_out -------------------------
// 16 rows/block (grid 2048): amortizes the 48 KB W_out LDS preload 4x.
__global__ __launch_bounds__(256) void k_feats(const u16* __restrict__ Lout,
        const float* __restrict__ Wout, const float* __restrict__ bout,
        float* __restrict__ Ft) {
    __shared__ __align__(16) float Wl[12 * 1024];
    for (int i = threadIdx.x; i < 12 * 1024; i += 256) Wl[i] = Wout[i];
    __syncthreads();
    int wv = threadIdx.x >> 6, lane = threadIdx.x & 63;
    #pragma unroll
    for (int rr = 0; rr < 4; ++rr) {
        size_t row = (size_t)blockIdx.x * 16 + rr * 4 + wv;
        const uint4* xr = (const uint4*)(Lout + row * 1024);
        float acc[12];
        #pragma unroll
        for (int tg = 0; tg < 12; ++tg) acc[tg] = 0.f;
        #pragma unroll
        for (int c = 0; c < 2; ++c) {
            int e8 = lane + (c << 6);
            uint4 xv = xr[e8];
            float x0 = flo(xv.x), x1 = fhi(xv.x);
            float x2 = flo(xv.y), x3 = fhi(xv.y);
            float x4 = flo(xv.z), x5 = fhi(xv.z);
            float x6 = flo(xv.w), x7 = fhi(xv.w);
            #pragma unroll
            for (int tg = 0; tg < 12; ++tg) {
                const float* wpt = &Wl[tg * 1024 + (e8 << 3)];
                float4 wa = *(const float4*)wpt;
                float4 wb = *(const float4*)(wpt + 4);
                acc[tg] += x0 * wa.x + x1 * wa.y + x2 * wa.z + x3 * wa.w
                         + x4 * wb.x + x5 * wb.y + x6 * wb.z + x7 * wb.w;
            }
        }
        #pragma unroll
        for (int tg = 0; tg < 12; ++tg) {
            #pragma unroll
            for (int off = 32; off > 0; off >>= 1)
                acc[tg] += __shfl_xor(acc[tg], off);
        }
        float v = 0.f;
        #pragma unroll
        for (int tg = 0; tg < 12; ++tg)
            if (lane == tg) v = acc[tg];
        if (lane < 12) Ft[row * 12 + lane] = v + bout[lane];
    }
}

// --- Kernel 5: Viterbi per batch (1 wave). ---------------------------------
__global__ __launch_bounds__(64) void k_viterbi(const float* __restrict__ Ft,
        const float* __restrict__ trans, float* __restrict__ out) {
    int b = blockIdx.x;
    int lane = threadIdx.x;
    __shared__ unsigned char bps[512][12];
    float tr[12];
    #pragma unroll
    for (int p = 0; p < 12; ++p)
        tr[p] = (lane < 12) ? trans[lane * 12 + p] : 0.f;
    float fv = (lane == TAG_START) ? 0.f : NEGV;
    const float* fb = Ft + (size_t)b * 512 * 12;
    for (int s = 0; s < 512; ++s) {
        float m = -3.4e38f;
        int bp = 0;
        #pragma unroll
        for (int p = 0; p < 12; ++p) {
            float v = __shfl(fv, p) + tr[p];
            if (v > m) { m = v; bp = p; }
        }
        float feat = (lane < 12) ? fb[s * 12 + lane] : 0.f;
        fv = m + feat;
        if (lane < 12) bps[s][lane] = (unsigned char)bp;
    }
    float term = fv + ((lane < 12) ? trans[TAG_STOP * 12 + lane] : 0.f);
    __syncthreads();
    float best = -3.4e38f; int tag = 0;
    #pragma unroll
    for (int p = 0; p < 12; ++p) {
        float v = __shfl(term, p);
        if (v > best) { best = v; tag = p; }
    }
    if (lane == 0) {
        out[b] = best;
        int tg = tag;
        for (int s = 511; s >= 0; --s) {
            out[64 + (size_t)b * 512 + s] = (float)tg;
            tg = bps[s][tg];
        }
    }
}

extern "C" void kernel_launch(void* const* d_in, const int* in_sizes, int n_in,
                              void* d_out, int out_size, void* d_ws, size_t ws_size,
                              hipStream_t stream) {
    const int*   sent   = (const int*)  d_in[0];
    const float* emb    = (const float*)d_in[1];
    const float* W_ih_f = (const float*)d_in[2];
    const float* W_hh_f = (const float*)d_in[3];
    const float* b_f    = (const float*)d_in[4];
    const float* W_ih_b = (const float*)d_in[5];
    const float* W_hh_b = (const float*)d_in[6];
    const float* b_b    = (const float*)d_in[7];
    const float* W_out  = (const float*)d_in[8];
    const float* b_out  = (const float*)d_in[9];
    const float* trans  = (const float*)d_in[10];
    float* out = (float*)d_out;

    char* wsB = (char*)d_ws;
    size_t off = 0;
    uint32* Wn2    = (uint32*)(wsB + off); off += 1048576;
    float*  sS     = (float*) (wsB + off); off += 16384;
    u16*    Wihb   = (u16*)   (wsB + off); off += 4194304;
    float*  biascat= (float*) (wsB + off); off += 16384;
    float*  Ft     = (float*) (wsB + off); off += 1572864;
    u16*    Lout   = (u16*)   (wsB + off); off += 67108864;
    size_t fixed = off;
    u16*    Gxc    = (u16*)   (wsB + off);

    int NB = 64;
    while (NB > 2 && fixed + (size_t)NB * 4194304ull > ws_size) NB >>= 1;

    k_packw<<<4096, 256, 0, stream>>>(W_ih_f, W_ih_b, b_f, b_b, Wihb, biascat);
    k_pack <<<4096, 64, 0, stream>>>(W_hh_f, W_hh_b, Wn2, sS);
    for (int c = 0; c < 64; c += NB) {
        k_gemm<<<NB * 128, 256, 0, stream>>>(sent, emb, Wihb, biascat, Gxc, c);
        k_lstm<<<NB * 2, 1024, 0, stream>>>(Gxc, Wn2, sS, Lout, c);
    }
    k_feats  <<<2048, 256, 0, stream>>>(Lout, W_out, b_out, Ft);
    k_viterbi<<<64, 64, 0, stream>>>(Ft, trans, out);
}

// Round 19
// 1628.904 us; speedup vs baseline: 3.3079x; 1.0353x over previous
//
#include <hip/hip_runtime.h>
#include <cmath>

// Problem constants
#define NTAG    12
#define TAG_START 10
#define TAG_STOP  11
#define NEGV    (-10000.0f)

typedef unsigned int uint32;
typedef unsigned short u16;
typedef __attribute__((ext_vector_type(8))) short bf16x8;
typedef __attribute__((ext_vector_type(4))) float f32x4;

#define SDOT8(a, b, c) __builtin_amdgcn_sdot8((int)(a), (int)(b), (c), false)

// bf16 <-> f32 helpers
__device__ inline float b2f(u16 h) {
    union { uint32 u; float f; } v; v.u = ((uint32)h) << 16; return v.f;
}
__device__ inline u16 f2b(float f) {
    union { float f; uint32 u; } v; v.f = f;
    uint32 u = v.u;
    uint32 r = (u + 0x7FFFu + ((u >> 16) & 1u)) >> 16;
    return (u16)r;
}
__device__ inline uint32 f2b2(float a, float b) {
    return (uint32)f2b(a) | ((uint32)f2b(b) << 16);
}
__device__ inline float flo(uint32 u) {
    union { uint32 u; float f; } v; v.u = u << 16; return v.f;
}
__device__ inline float fhi(uint32 u) {
    union { uint32 u; float f; } v; v.u = u & 0xFFFF0000u; return v.f;
}

// ---------------------------------------------------------------------------
// ws layout (bytes):
//   Wn2     u32 [2 dir][64 oct][512 u][4 ty]  1,048,576  int4 W_hh (dot8 nibbles)
//   sS      f32 [2 dir][512 u][4 ty]             16,384  per-row scale
//   Wihb    u16 [4096][512]                   4,194,304  bf16 W_ih (f then b)
//   biascat f32 [4096]                           16,384  bias (f then b)
//   Ft      f32 [32768][12]                   1,572,864  feats
//   Lout    bf16 [32768][1024]               67,108,864  bilstm output
//   embb    u16 [50000][512]                 51,200,000  bf16 emb (optional)
//   Gx      bf16 [NB*512][4096]           NB*4,194,304   gate preacts (chunk)
// ---------------------------------------------------------------------------

// --- Kernel 0a: pack W_ih + bias to bf16 concat ------------------------------
__global__ __launch_bounds__(256) void k_packw(const float* __restrict__ Wf,
        const float* __restrict__ Wb, const float* __restrict__ bf,
        const float* __restrict__ bb, u16* __restrict__ Wihb,
        float* __restrict__ biascat) {
    int g = blockIdx.x;           // 0..4095
    const float* src = (g < 2048) ? (Wf + (size_t)g * 512)
                                  : (Wb + (size_t)(g - 2048) * 512);
    for (int k = threadIdx.x; k < 512; k += 256)
        Wihb[(size_t)g * 512 + k] = f2b(src[k]);
    if (threadIdx.x == 0)
        biascat[g] = (g < 2048) ? bf[g] : bb[g - 2048];
}

// --- Kernel 0b: emb f32 -> bf16 (same RNE f2b as the inline path: Gx is
// bit-identical either way). 25,600,000 elems, 8 per thread, grid 12500.
__global__ __launch_bounds__(256) void k_packe(const float* __restrict__ emb,
                                               u16* __restrict__ embb) {
    size_t idx = ((size_t)blockIdx.x * 256 + threadIdx.x) * 8;
    float4 f0 = *(const float4*)(emb + idx);
    float4 f1 = *(const float4*)(emb + idx + 4);
    uint4 pk;
    pk.x = f2b2(f0.x, f0.y); pk.y = f2b2(f0.z, f0.w);
    pk.z = f2b2(f1.x, f1.y); pk.w = f2b2(f1.z, f1.w);
    *(uint4*)(embb + idx) = pk;
}

// --- Kernel 1: pack W_hh as dot8 nibbles, [dir][oct][unit][ty] layout. ------
__global__ __launch_bounds__(64) void k_pack(const float* __restrict__ Wf,
                                             const float* __restrict__ Wb,
                                             uint32* __restrict__ Wn2,
                                             float* __restrict__ sS) {
    int e = blockIdx.x;                 // 0..4095
    int dir = e >> 11, g = e & 2047;
    int ty = g >> 9, u = g & 511;
    const float* W = (dir ? Wb : Wf) + (size_t)g * 512;
    int t = threadIdx.x;                // oct index
    float w[8];
    float m = 0.f;
    #pragma unroll
    for (int i = 0; i < 8; ++i) {
        w[i] = W[t * 8 + i];
        m = fmaxf(m, fabsf(w[i]));
    }
    #pragma unroll
    for (int off = 32; off > 0; off >>= 1)
        m = fmaxf(m, __shfl_xor(m, off));
    float s = (m > 0.f) ? (m / 7.f) : 1.f;
    float inv = 1.f / s;
    uint32 d = 0;
    #pragma unroll
    for (int k = 0; k < 8; ++k) {
        uint32 qv = (uint32)((int)rintf(w[k] * inv)) & 0xFu;
        d |= qv << (4 * k);
    }
    Wn2[(((size_t)dir * 64 + t) * 512 + u) * 4 + ty] = d;
    if (t == 0) sS[((size_t)dir * 512 + u) * 4 + ty] = s / 7.f;
}

// --- Kernel 2: fused gather + input GEMM, bf16 MFMA --------------------------
// use_embb: A staged with single uint4 loads from pre-converted bf16 emb
// (halves A bytes, removes 32 f2b/thread/K-step); else inline-convert path.
__global__ __launch_bounds__(256) void k_gemm(const int* __restrict__ sent,
        const float* __restrict__ emb, const u16* __restrict__ embb,
        int use_embb, const u16* __restrict__ Wihb,
        const float* __restrict__ biascat, u16* __restrict__ Gxc, int b0c) {
    __shared__ __align__(16) u16 As[128][72];
    __shared__ __align__(16) u16 Bs[128][72];
    __shared__ int ssent[128];

    int bid = blockIdx.x;
    int nb = bid & 31, mb = bid >> 5;
    int M0 = mb << 7, N0 = nb << 7;
    int t = threadIdx.x;
    int w = t >> 6, l = t & 63;
    int wr = w >> 1, wc = w & 1;

    if (t < 128) ssent[t] = sent[b0c * 512 + M0 + t];

    f32x4 zero = {0.f, 0.f, 0.f, 0.f};
    f32x4 acc[4][4];
    #pragma unroll
    for (int i = 0; i < 4; ++i)
        #pragma unroll
        for (int j = 0; j < 4; ++j) acc[i][j] = zero;

    int srow = t >> 3;
    int skc  = (t & 7) << 3;
    __syncthreads();

    for (int k0 = 0; k0 < 512; k0 += 64) {
        if (use_embb) {
            #pragma unroll
            for (int i = 0; i < 4; ++i) {
                int r = srow + (i << 5);
                uint4 pa = *(const uint4*)(embb + (size_t)ssent[r] * 512 + k0 + skc);
                *(uint4*)&As[r][skc] = pa;
                uint4 pb = *(const uint4*)(Wihb + (size_t)(N0 + r) * 512 + k0 + skc);
                *(uint4*)&Bs[r][skc] = pb;
            }
        } else {
            #pragma unroll
            for (int i = 0; i < 4; ++i) {
                int r = srow + (i << 5);
                const float* srcA = emb + (size_t)ssent[r] * 512 + k0 + skc;
                float4 f0 = *(const float4*)srcA;
                float4 f1 = *(const float4*)(srcA + 4);
                uint4 pa;
                pa.x = f2b2(f0.x, f0.y); pa.y = f2b2(f0.z, f0.w);
                pa.z = f2b2(f1.x, f1.y); pa.w = f2b2(f1.z, f1.w);
                *(uint4*)&As[r][skc] = pa;
                uint4 pb = *(const uint4*)(Wihb + (size_t)(N0 + r) * 512 + k0 + skc);
                *(uint4*)&Bs[r][skc] = pb;
            }
        }
        __syncthreads();
        int lrow = l & 15, lk = (l >> 4) << 3;
        #pragma unroll
        for (int kk = 0; kk < 64; kk += 32) {
            bf16x8 af[4], bfr[4];
            #pragma unroll
            for (int i = 0; i < 4; ++i)
                af[i] = *(const bf16x8*)&As[(wr << 6) + (i << 4) + lrow][kk + lk];
            #pragma unroll
            for (int j = 0; j < 4; ++j)
                bfr[j] = *(const bf16x8*)&Bs[(wc << 6) + (j << 4) + lrow][kk + lk];
            #pragma unroll
            for (int i = 0; i < 4; ++i)
                #pragma unroll
                for (int j = 0; j < 4; ++j)
                    acc[i][j] = __builtin_amdgcn_mfma_f32_16x16x32_bf16(
                        af[i], bfr[j], acc[i][j], 0, 0, 0);
        }
        __syncthreads();
    }

    int lrow = l & 15, lq = l >> 4;
    #pragma unroll
    for (int j = 0; j < 4; ++j) {
        int col = N0 + (wc << 6) + (j << 4) + lrow;
        float bv = biascat[col];
        #pragma unroll
        for (int i = 0; i < 4; ++i) {
            int rbase = M0 + (wr << 6) + (i << 4) + (lq << 2);
            #pragma unroll
            for (int r = 0; r < 4; ++r)
                Gxc[(size_t)(rbase + r) * 4096 + col] = f2b(acc[i][j][r] + bv);
        }
    }
}

// 16 dot8 for a 4-oct group: h = 4 h-dwords, w0..w3 = per-oct gate dwords
#define D8_GRP(h, w0, w1, w2, w3)                                          \
    do {                                                                   \
        a0 = SDOT8((h).x, (w0).x, a0); a1 = SDOT8((h).x, (w0).y, a1);      \
        a2 = SDOT8((h).x, (w0).z, a2); a3 = SDOT8((h).x, (w0).w, a3);      \
        a0 = SDOT8((h).y, (w1).x, a0); a1 = SDOT8((h).y, (w1).y, a1);      \
        a2 = SDOT8((h).y, (w1).z, a2); a3 = SDOT8((h).y, (w1).w, a3);      \
        a0 = SDOT8((h).z, (w2).x, a0); a1 = SDOT8((h).z, (w2).y, a1);      \
        a2 = SDOT8((h).z, (w2).z, a2); a3 = SDOT8((h).z, (w2).w, a3);      \
        a0 = SDOT8((h).w, (w3).x, a0); a1 = SDOT8((h).w, (w3).y, a1);      \
        a2 = SDOT8((h).w, (w3).z, a2); a3 = SDOT8((h).w, (w3).w, a3);      \
    } while (0)

// --- Kernel 3: BiLSTM recurrence (round-14 version, proven 1170 us) ---------
__global__ __launch_bounds__(1024, 4) void k_lstm(const u16* __restrict__ Gxc,
        const uint32* __restrict__ Wn2, const float* __restrict__ sS,
        u16* __restrict__ Lout, int b0c) {
    int bid = blockIdx.x;
    int dir, slot;
    if (gridDim.x >= 8) {
        int xid = bid & 7, q = bid >> 3;
        dir  = xid >> 2;                 // XCDs 0-3 dir0, 4-7 dir1
        slot = (xid & 3) | (q << 2);
    } else {
        dir  = bid & 1;
        slot = bid >> 1;
    }
    int b  = b0c + slot;
    int lb = slot;

    __shared__ __align__(16) uint32 wlds[16][2048];  // 128 KB: octs 0..15
    __shared__ __align__(16) uint32 hq4[2][64];      // i4 h, parity dbuf
    __shared__ __align__(16) int4   pbuf[512];       // 8 KB upper-half partials

    int t = threadIdx.x;
    int u = t & 511;                    // owned unit
    int half = t >> 9;                  // 0 lower, 1 upper (wave-aligned)
    if (t < 128) hq4[t >> 6][t & 63] = 0u;
    float cs = 0.f;

    const uint32* wsrc = Wn2 + (size_t)dir * (64 * 2048);
    {   // preload LDS tier: 8192 uint4, 1024 threads x 8
        const uint4* src = (const uint4*)wsrc;
        uint4* dst = (uint4*)wlds;
        #pragma unroll
        for (int i = 0; i < 8; ++i)
            dst[t + i * 1024] = src[t + i * 1024];
    }
    // register tier request (compiler may sink; harmless)
    const uint32* rp = wsrc + (size_t)(half ? 40 : 16) * 2048 + (u << 2);
    uint4 wreg[8];
    #pragma unroll
    for (int i = 0; i < 8; ++i)
        wreg[i] = *(const uint4*)(rp + (size_t)i * 2048);

    float4 sc = {0.f, 0.f, 0.f, 0.f};
    const u16* gx = Gxc;
    if (half == 0) {
        sc = *(const float4*)(sS + ((size_t)dir * 512 + u) * 4);
        gx = Gxc + (size_t)lb * 512 * 4096 + (dir << 11) + u;
    }
    int ldsg0 = half ? 2 : 0;                                 // LDS h-groups
    int regg0 = half ? 10 : 4;                                // reg h-groups
    const uint32* sp = wsrc + (size_t)(half ? 48 : 24) * 2048 + (u << 2);
    int hgs0 = half ? 12 : 6;                                 // streamed h-groups
    int sh = (u & 7) << 2;
    __syncthreads();

    for (int si = 0; si < 512; ++si) {
        int s = dir ? (511 - si) : si;
        int par = si & 1;
        const uint4* hg = (const uint4*)hq4[par];

        // early Gx preact prefetch (lower half; L3 latency hides under dots)
        u16 g0v = 0, g1v = 0, g2v = 0, g3v = 0;
        if (half == 0) {
            const u16* gs = gx + (size_t)s * 4096;
            g0v = gs[0]; g1v = gs[512]; g2v = gs[1024]; g3v = gs[1536];
        }

        int a0 = 0, a1 = 0, a2 = 0, a3 = 0;

        // streamed tier: 4 groups (16 octs)
        #pragma unroll
        for (int p = 0; p < 4; ++p) {
            uint4 h  = hg[hgs0 + p];
            uint4 w0 = *(const uint4*)(sp + (size_t)(4 * p + 0) * 2048);
            uint4 w1 = *(const uint4*)(sp + (size_t)(4 * p + 1) * 2048);
            uint4 w2 = *(const uint4*)(sp + (size_t)(4 * p + 2) * 2048);
            uint4 w3 = *(const uint4*)(sp + (size_t)(4 * p + 3) * 2048);
            D8_GRP(h, w0, w1, w2, w3);
        }
        // register tier: 2 groups (8 octs)
        {
            uint4 h = hg[regg0];
            D8_GRP(h, wreg[0], wreg[1], wreg[2], wreg[3]);
            h = hg[regg0 + 1];
            D8_GRP(h, wreg[4], wreg[5], wreg[6], wreg[7]);
        }
        // LDS tier: 2 groups (8 octs)
        #pragma unroll
        for (int p = 0; p < 2; ++p) {
            int gp = ldsg0 + p;
            uint4 h  = hg[gp];
            uint4 w0 = *(const uint4*)&wlds[4 * gp + 0][u << 2];
            uint4 w1 = *(const uint4*)&wlds[4 * gp + 1][u << 2];
            uint4 w2 = *(const uint4*)&wlds[4 * gp + 2][u << 2];
            uint4 w3 = *(const uint4*)&wlds[4 * gp + 3][u << 2];
            D8_GRP(h, w0, w1, w2, w3);
        }

        if (half) pbuf[u] = make_int4(a0, a1, a2, a3);
        __syncthreads();

        if (half == 0) {
            int4 pu = pbuf[u];
            a0 += pu.x; a1 += pu.y; a2 += pu.z; a3 += pu.w;
            float pi = b2f(g0v) + sc.x * (float)a0;
            float pf = b2f(g1v) + sc.y * (float)a1;
            float pg = b2f(g2v) + sc.z * (float)a2;
            float po = b2f(g3v) + sc.w * (float)a3;
            float iv  = 1.f / (1.f + expf(-pi));
            float fvv = 1.f / (1.f + expf(-pf));
            float gv  = tanhf(pg);
            float ov  = 1.f / (1.f + expf(-po));
            float cn = fvv * cs + iv * gv;
            float hn = ov * tanhf(cn);
            cs = cn;
            uint32 v = (((uint32)(int)rintf(hn * 7.f)) & 0xFu) << sh;
            v |= __shfl_xor(v, 1); v |= __shfl_xor(v, 2); v |= __shfl_xor(v, 4);
            if ((u & 7) == 0) hq4[par ^ 1][u >> 3] = v;
            Lout[((size_t)b * 512 + s) * 1024 + (dir << 9) + u] = f2b(hn);
        }
        __syncthreads();
    }
}

// --- Kernel 4: feats = Lout(bf16) @ W_out^T + b_out, 16 rows/block ----------
__global__ __launch_bounds__(256) void k_feats(const u16* __restrict__ Lout,
        const float* __restrict__ Wout, const float* __restrict__ bout,
        float* __restrict__ Ft) {
    __shared__ __align__(16) float Wl[12 * 1024];
    for (int i = threadIdx.x; i < 12 * 1024; i += 256) Wl[i] = Wout[i];
    __syncthreads();
    int wv = threadIdx.x >> 6, lane = threadIdx.x & 63;
    #pragma unroll
    for (int rr = 0; rr < 4; ++rr) {
        size_t row = (size_t)blockIdx.x * 16 + rr * 4 + wv;
        const uint4* xr = (const uint4*)(Lout + row * 1024);
        float acc[12];
        #pragma unroll
        for (int tg = 0; tg < 12; ++tg) acc[tg] = 0.f;
        #pragma unroll
        for (int c = 0; c < 2; ++c) {
            int e8 = lane + (c << 6);
            uint4 xv = xr[e8];
            float x0 = flo(xv.x), x1 = fhi(xv.x);
            float x2 = flo(xv.y), x3 = fhi(xv.y);
            float x4 = flo(xv.z), x5 = fhi(xv.z);
            float x6 = flo(xv.w), x7 = fhi(xv.w);
            #pragma unroll
            for (int tg = 0; tg < 12; ++tg) {
                const float* wpt = &Wl[tg * 1024 + (e8 << 3)];
                float4 wa = *(const float4*)wpt;
                float4 wb = *(const float4*)(wpt + 4);
                acc[tg] += x0 * wa.x + x1 * wa.y + x2 * wa.z + x3 * wa.w
                         + x4 * wb.x + x5 * wb.y + x6 * wb.z + x7 * wb.w;
            }
        }
        #pragma unroll
        for (int tg = 0; tg < 12; ++tg) {
            #pragma unroll
            for (int off = 32; off > 0; off >>= 1)
                acc[tg] += __shfl_xor(acc[tg], off);
        }
        float v = 0.f;
        #pragma unroll
        for (int tg = 0; tg < 12; ++tg)
            if (lane == tg) v = acc[tg];
        if (lane < 12) Ft[row * 12 + lane] = v + bout[lane];
    }
}

// --- Kernel 5: Viterbi per batch (1 wave). ---------------------------------
__global__ __launch_bounds__(64) void k_viterbi(const float* __restrict__ Ft,
        const float* __restrict__ trans, float* __restrict__ out) {
    int b = blockIdx.x;
    int lane = threadIdx.x;
    __shared__ unsigned char bps[512][12];
    float tr[12];
    #pragma unroll
    for (int p = 0; p < 12; ++p)
        tr[p] = (lane < 12) ? trans[lane * 12 + p] : 0.f;
    float fv = (lane == TAG_START) ? 0.f : NEGV;
    const float* fb = Ft + (size_t)b * 512 * 12;
    for (int s = 0; s < 512; ++s) {
        float m = -3.4e38f;
        int bp = 0;
        #pragma unroll
        for (int p = 0; p < 12; ++p) {
            float v = __shfl(fv, p) + tr[p];
            if (v > m) { m = v; bp = p; }
        }
        float feat = (lane < 12) ? fb[s * 12 + lane] : 0.f;
        fv = m + feat;
        if (lane < 12) bps[s][lane] = (unsigned char)bp;
    }
    float term = fv + ((lane < 12) ? trans[TAG_STOP * 12 + lane] : 0.f);
    __syncthreads();
    float best = -3.4e38f; int tag = 0;
    #pragma unroll
    for (int p = 0; p < 12; ++p) {
        float v = __shfl(term, p);
        if (v > best) { best = v; tag = p; }
    }
    if (lane == 0) {
        out[b] = best;
        int tg = tag;
        for (int s = 511; s >= 0; --s) {
            out[64 + (size_t)b * 512 + s] = (float)tg;
            tg = bps[s][tg];
        }
    }
}

extern "C" void kernel_launch(void* const* d_in, const int* in_sizes, int n_in,
                              void* d_out, int out_size, void* d_ws, size_t ws_size,
                              hipStream_t stream) {
    const int*   sent   = (const int*)  d_in[0];
    const float* emb    = (const float*)d_in[1];
    const float* W_ih_f = (const float*)d_in[2];
    const float* W_hh_f = (const float*)d_in[3];
    const float* b_f    = (const float*)d_in[4];
    const float* W_ih_b = (const float*)d_in[5];
    const float* W_hh_b = (const float*)d_in[6];
    const float* b_b    = (const float*)d_in[7];
    const float* W_out  = (const float*)d_in[8];
    const float* b_out  = (const float*)d_in[9];
    const float* trans  = (const float*)d_in[10];
    float* out = (float*)d_out;

    char* wsB = (char*)d_ws;
    size_t off = 0;
    uint32* Wn2    = (uint32*)(wsB + off); off += 1048576;
    float*  sS     = (float*) (wsB + off); off += 16384;
    u16*    Wihb   = (u16*)   (wsB + off); off += 4194304;
    float*  biascat= (float*) (wsB + off); off += 16384;
    float*  Ft     = (float*) (wsB + off); off += 1572864;
    u16*    Lout   = (u16*)   (wsB + off); off += 67108864;
    size_t fixed = off;

    // optional bf16-emb buffer (51.2 MB), only if ws still fits NB=64 Gx
    size_t embb_need = 51200000ull;
    u16* embb = (u16*)(wsB + fixed);
    int use_embb = 0;
    size_t fixed2 = fixed;
    if (fixed + embb_need + 64ull * 4194304ull <= ws_size) {
        use_embb = 1;
        fixed2 = fixed + embb_need;
    }
    u16* Gxc = (u16*)(wsB + fixed2);

    int NB = 64;
    while (NB > 2 && fixed2 + (size_t)NB * 4194304ull > ws_size) NB >>= 1;

    k_packw<<<4096, 256, 0, stream>>>(W_ih_f, W_ih_b, b_f, b_b, Wihb, biascat);
    k_pack <<<4096, 64, 0, stream>>>(W_hh_f, W_hh_b, Wn2, sS);
    if (use_embb)
        k_packe<<<12500, 256, 0, stream>>>(emb, embb);
    for (int c = 0; c < 64; c += NB) {
        k_gemm<<<NB * 128, 256, 0, stream>>>(sent, emb, embb, use_embb,
                                             Wihb, biascat, Gxc, c);
        k_lstm<<<NB * 2, 1024, 0, stream>>>(Gxc, Wn2, sS, Lout, c);
    }
    k_feats  <<<2048, 256, 0, stream>>>(Lout, W_out, b_out, Ft);
    k_viterbi<<<64, 64, 0, stream>>>(Ft, trans, out);
}